// Round 3
// baseline (191.619 us; speedup 1.0000x reference)
//
#include <hip/hip_runtime.h>
#include <hip/hip_bf16.h>

#define BN 4
#define CC 256
#define C8 32
#define NN 4096
#define PROJ_ROWS 320

typedef __attribute__((ext_vector_type(8))) short short8;
typedef __attribute__((ext_vector_type(4))) float f32x4;

__device__ __forceinline__ unsigned short f2bf(float f) {
    unsigned u = __builtin_bit_cast(unsigned, f);
    unsigned r = (u + 0x7fffu + ((u >> 16) & 1u)) >> 16;
    return (unsigned short)r;
}

// ---------------------------------------------------------------------------
// Projection GEMM, single-barrier version (unchanged from baseline).
// ---------------------------------------------------------------------------
__global__ __launch_bounds__(256) void proj_kernel(
    const float* __restrict__ x,
    const float* __restrict__ Wq, const float* __restrict__ bq,
    const float* __restrict__ Wk, const float* __restrict__ bk,
    const float* __restrict__ Wv, const float* __restrict__ bv,
    unsigned short* __restrict__ proj, unsigned short* __restrict__ qT)
{
    int bid = blockIdx.x;
    int b = bid >> 6, nt = bid & 63;
    int n0 = nt * 64;
    int tid = threadIdx.x;
    int w = tid >> 6, l = tid & 63, l15 = l & 15, lq = l >> 4;

    // Xt[n 64][c 256], stride 264 shorts = 528 B (16B-aligned rows)
    __shared__ alignas(16) unsigned short Xt[64][264];

    int c_l = tid >> 3;          // 0..31
    int nb  = (tid & 7) * 8;     // 0..56

    // stage all 8 c-chunks, then ONE barrier
#pragma unroll
    for (int kc = 0; kc < 8; kc++) {
        const float* xp = x + ((size_t)(b * CC + kc * 32 + c_l)) * NN + n0 + nb;
        float4 x0 = *(const float4*)xp;
        float4 x1 = *(const float4*)(xp + 4);
        float t[8] = {x0.x, x0.y, x0.z, x0.w, x1.x, x1.y, x1.z, x1.w};
#pragma unroll
        for (int e = 0; e < 8; e++) Xt[nb + e][kc * 32 + c_l] = f2bf(t[e]);
    }
    __syncthreads();

    f32x4 acc[5][4];   // wave owns o-groups g = 5w..5w+4 (16 rows each)
#pragma unroll
    for (int gi = 0; gi < 5; gi++)
#pragma unroll
        for (int mi = 0; mi < 4; mi++) acc[gi][mi] = (f32x4){0.f, 0.f, 0.f, 0.f};

    for (int kc = 0; kc < 8; kc++) {
        float4 wf[5][2];
#pragma unroll
        for (int gi = 0; gi < 5; gi++) {
            int og = (w * 5 + gi) * 16 + l15;
            const float* wrow = (og < 32) ? (Wq + (size_t)og * CC)
                              : (og < 64) ? (Wk + (size_t)(og - 32) * CC)
                                          : (Wv + (size_t)(og - 64) * CC);
            const float* wp = wrow + kc * 32 + lq * 8;
            wf[gi][0] = *(const float4*)wp;
            wf[gi][1] = *(const float4*)(wp + 4);
        }
#pragma unroll
        for (int gi = 0; gi < 5; gi++) {
            unsigned short a8[8] __attribute__((aligned(16)));
            float tw[8] = {wf[gi][0].x, wf[gi][0].y, wf[gi][0].z, wf[gi][0].w,
                           wf[gi][1].x, wf[gi][1].y, wf[gi][1].z, wf[gi][1].w};
#pragma unroll
            for (int e = 0; e < 8; e++) a8[e] = f2bf(tw[e]);
            short8 af = *(const short8*)a8;
#pragma unroll
            for (int mi = 0; mi < 4; mi++) {
                short8 bf = *(const short8*)&Xt[mi * 16 + l15][kc * 32 + lq * 8];
                acc[gi][mi] = __builtin_amdgcn_mfma_f32_16x16x32_bf16(af, bf, acc[gi][mi], 0, 0, 0);
            }
        }
    }

    // epilogue: bias + bf16 store. C/D: row = lq*4+r (within group), col = l15.
#pragma unroll
    for (int gi = 0; gi < 5; gi++) {
#pragma unroll
        for (int r = 0; r < 4; r++) {
            int og = (w * 5 + gi) * 16 + lq * 4 + r;
            float bias = (og < 32) ? bq[og] : (og < 64) ? bk[og - 32] : bv[og - 64];
#pragma unroll
            for (int mi = 0; mi < 4; mi++) {
                int n = n0 + mi * 16 + l15;
                unsigned short v16 = f2bf(acc[gi][mi][r] + bias);
                if (og < 32) {
                    qT[((size_t)b * NN + n) * C8 + og] = v16;
                } else {
                    proj[((size_t)b * PROJ_ROWS + og) * NN + n] = v16;
                }
            }
        }
    }
}

// ---------------------------------------------------------------------------
// Flash attention over the query axis (softmax over n), no max subtraction.
// v3 = v1 (64-n per barrier, single-barrier loop, scalar Opart epilogue)
// + PHASE STAGGER: co-resident blocks (same CU slot = bid>>8) start their
// n-loop at different tile offsets and wrap. The n-sum is order-independent,
// so correctness is unchanged; the point is to break the phase-lock between
// the ~4 co-resident blocks so one block's MFMA burst covers another's
// load/exp/barrier window.
// ---------------------------------------------------------------------------
template<int NSPLIT, bool FINAL>
__global__ __launch_bounds__(256, 4) void attn_kernel(
    const unsigned short* __restrict__ proj,
    const unsigned short* __restrict__ qT,
    const float* __restrict__ x,
    const float* __restrict__ gamma_p,
    float* __restrict__ out,
    float* __restrict__ Opart,
    float* __restrict__ Lpart)
{
    constexpr int ITERS = 64 / NSPLIT;
    int bid = blockIdx.x;
    int h   = bid >> 8;
    int low = bid & 255;
    int xcd = low & 7;
    int b = xcd >> 1;
    int mtile = ((low >> 3) << 1) | (xcd & 1);
    int m0 = mtile * 64;
    int nbase = h * (ITERS * 64);

    // stagger: CU-slot s starts at tile s*(ITERS/4), wraps mod ITERS
    int phase = ((bid >> 8) & 3) * (ITERS / 4);

    int tid = threadIdx.x;
    int w = tid >> 6, l = tid & 63, l15 = l & 15, lq = l >> 4;

    __shared__ alignas(16) unsigned short ps[2][64][72];  // [buf][m][n]
    __shared__ float red[4][64];
    __shared__ float Ltot[64];

    const unsigned short* kbase = proj + ((size_t)b * PROJ_ROWS + C8) * NN;
    const unsigned short* vbase = proj + ((size_t)b * PROJ_ROWS + 64) * NN;
    const unsigned short* qbase = qT + (size_t)b * NN * C8;

    // k B-operand fragments (held all kernel): lane = k[c8=lq*8+j][m]
    short8 kfrag[4];
#pragma unroll
    for (int mi = 0; mi < 4; mi++) {
        int col = m0 + mi * 16 + l15;
        unsigned short t8[8] __attribute__((aligned(16)));
#pragma unroll
        for (int j = 0; j < 8; j++)
            t8[j] = kbase[(size_t)(lq * 8 + j) * NN + col];
        kfrag[mi] = *(const short8*)t8;
    }

    f32x4 O[4][4];
#pragma unroll
    for (int ci = 0; ci < 4; ci++)
#pragma unroll
        for (int mi = 0; mi < 4; mi++) O[ci][mi] = (f32x4){0.f, 0.f, 0.f, 0.f};
    float runS[4] = {0.f, 0.f, 0.f, 0.f};

    // prologue: S_tile(phase), exp, write ps[0]
    {
        int tt = phase;
        short8 qfrag = *(const short8*)(qbase
                       + (size_t)(nbase + tt * 64 + 16 * w + l15) * C8 + lq * 8);
#pragma unroll
        for (int mi = 0; mi < 4; mi++) {
            f32x4 S = __builtin_amdgcn_mfma_f32_16x16x32_bf16(
                qfrag, kfrag[mi], (f32x4){0.f, 0.f, 0.f, 0.f}, 0, 0, 0);
            float p0 = __expf(S[0]);
            float p1 = __expf(S[1]);
            float p2 = __expf(S[2]);
            float p3 = __expf(S[3]);
            runS[mi] += (p0 + p1) + (p2 + p3);
            unsigned pk0 = (unsigned)f2bf(p0) | ((unsigned)f2bf(p1) << 16);
            unsigned pk1 = (unsigned)f2bf(p2) | ((unsigned)f2bf(p3) << 16);
            *(uint2*)&ps[0][mi * 16 + l15][16 * w + lq * 4] = make_uint2(pk0, pk1);
        }
    }

    for (int it = 0; it < ITERS; it++) {
        int tt = (it + phase) & (ITERS - 1);          // tile consumed this iter
        int n0c = nbase + tt * 64;
        __syncthreads();  // ps[it&1] visible; WAR on ps[(it+1)&1] cleared

        // PV: O[c,m] += V[c,n] . P[n,m]; wave w owns c in [64w,64w+64).
        const unsigned short* psrc = &ps[it & 1][0][0];
#pragma unroll
        for (int kh = 0; kh < 2; kh++) {
            short8 av[4];
#pragma unroll
            for (int ci = 0; ci < 4; ci++)
                av[ci] = *(const short8*)(vbase
                         + (size_t)(64 * w + ci * 16 + l15) * NN + n0c + kh * 32 + lq * 8);
            short8 bfr[4];
#pragma unroll
            for (int mi = 0; mi < 4; mi++)
                bfr[mi] = *(const short8*)(psrc + (mi * 16 + l15) * 72 + kh * 32 + lq * 8);
#pragma unroll
            for (int ci = 0; ci < 4; ci++)
#pragma unroll
                for (int mi = 0; mi < 4; mi++)
                    O[ci][mi] = __builtin_amdgcn_mfma_f32_16x16x32_bf16(
                        av[ci], bfr[mi], O[ci][mi], 0, 0, 0);
        }

        // S for tile tt(it+1), exp, write ps[(it+1)&1] — hidden until next barrier
        if (it + 1 < ITERS) {
            int tn = (it + 1 + phase) & (ITERS - 1);
            short8 qfrag = *(const short8*)(qbase
                           + (size_t)(nbase + tn * 64 + 16 * w + l15) * C8 + lq * 8);
            unsigned short* pdst = &ps[(it + 1) & 1][0][0];
#pragma unroll
            for (int mi = 0; mi < 4; mi++) {
                f32x4 S = __builtin_amdgcn_mfma_f32_16x16x32_bf16(
                    qfrag, kfrag[mi], (f32x4){0.f, 0.f, 0.f, 0.f}, 0, 0, 0);
                float p0 = __expf(S[0]);
                float p1 = __expf(S[1]);
                float p2 = __expf(S[2]);
                float p3 = __expf(S[3]);
                runS[mi] += (p0 + p1) + (p2 + p3);
                unsigned pk0 = (unsigned)f2bf(p0) | ((unsigned)f2bf(p1) << 16);
                unsigned pk1 = (unsigned)f2bf(p2) | ((unsigned)f2bf(p3) << 16);
                *(uint2*)(pdst + (mi * 16 + l15) * 72 + 16 * w + lq * 4) = make_uint2(pk0, pk1);
            }
        }
    }

    // column-sum reduction: cross-lane (n row-groups), then cross-wave
#pragma unroll
    for (int mi = 0; mi < 4; mi++) {
        float s = runS[mi];
        s += __shfl_xor(s, 16);
        s += __shfl_xor(s, 32);
        red[w][mi * 16 + l15] = s;
    }
    __syncthreads();
    if (tid < 64) Ltot[tid] = red[0][tid] + red[1][tid] + red[2][tid] + red[3][tid];
    __syncthreads();

    if constexpr (FINAL) {
        float gamma = gamma_p[0];
        float iv[4];
#pragma unroll
        for (int mi = 0; mi < 4; mi++) iv[mi] = 1.0f / Ltot[mi * 16 + l15];
#pragma unroll
        for (int ci = 0; ci < 4; ci++) {
#pragma unroll
            for (int mi = 0; mi < 4; mi++) {
                int m = m0 + mi * 16 + l15;
#pragma unroll
                for (int r = 0; r < 4; r++) {
                    int c = 64 * w + ci * 16 + lq * 4 + r;
                    size_t idx = ((size_t)b * CC + c) * NN + m;
                    out[idx] = gamma * (O[ci][mi][r] * iv[mi]) + x[idx];
                }
            }
        }
    } else {
        size_t p = ((size_t)h * BN + b) * 64 + mtile;
        if (tid < 64) Lpart[p * 64 + tid] = Ltot[tid];
        float* Ob = Opart + p * (size_t)(CC * 64);
#pragma unroll
        for (int ci = 0; ci < 4; ci++) {
#pragma unroll
            for (int mi = 0; mi < 4; mi++) {
#pragma unroll
                for (int r = 0; r < 4; r++) {
                    int c = 64 * w + ci * 16 + lq * 4 + r;
                    Ob[c * 64 + mi * 16 + l15] = O[ci][mi][r];
                }
            }
        }
    }
}

// ---------------------------------------------------------------------------
// Combine: out = gamma * (sum_h O_h) / (sum_h L_h) + x.
// Grid 1024: one block per (b, mt, c-quarter) for >1 block/CU.
// ---------------------------------------------------------------------------
template<int NSPLIT>
__global__ __launch_bounds__(256) void combine_kernel(
    const float* __restrict__ Opart, const float* __restrict__ Lpart,
    const float* __restrict__ x, const float* __restrict__ gamma_p,
    float* __restrict__ out)
{
    int bid = blockIdx.x;
    int cq = bid & 3;
    int mt = (bid >> 2) & 63;
    int b  = bid >> 8;
    int tid = threadIdx.x;
    int m4 = tid & 15, c16 = tid >> 4;
    float gamma = gamma_p[0];

    f32x4 Ls = (f32x4){0.f, 0.f, 0.f, 0.f};
#pragma unroll
    for (int h = 0; h < NSPLIT; h++) {
        size_t p = ((size_t)h * BN + b) * 64 + mt;
        Ls += *(const f32x4*)(Lpart + p * 64 + m4 * 4);
    }
    f32x4 inv;
#pragma unroll
    for (int j = 0; j < 4; j++) inv[j] = 1.0f / Ls[j];

#pragma unroll
    for (int cp = 0; cp < 4; cp++) {
        int c = cq * 64 + cp * 16 + c16;
        f32x4 acc = (f32x4){0.f, 0.f, 0.f, 0.f};
#pragma unroll
        for (int h = 0; h < NSPLIT; h++) {
            size_t p = ((size_t)h * BN + b) * 64 + mt;
            acc += *(const f32x4*)(Opart + p * (size_t)(CC * 64) + c * 64 + m4 * 4);
        }
        size_t idx = ((size_t)b * CC + c) * NN + mt * 64 + m4 * 4;
        f32x4 xv = *(const f32x4*)(x + idx);
        f32x4 o;
#pragma unroll
        for (int j = 0; j < 4; j++) o[j] = gamma * (acc[j] * inv[j]) + xv[j];
        *(f32x4*)(out + idx) = o;
    }
}

extern "C" void kernel_launch(void* const* d_in, const int* in_sizes, int n_in,
                              void* d_out, int out_size, void* d_ws, size_t ws_size,
                              hipStream_t stream) {
    const float* x     = (const float*)d_in[0];
    const float* Wq    = (const float*)d_in[1];
    const float* bq    = (const float*)d_in[2];
    const float* Wk    = (const float*)d_in[3];
    const float* bk    = (const float*)d_in[4];
    const float* Wv    = (const float*)d_in[5];
    const float* bv    = (const float*)d_in[6];
    const float* gamma = (const float*)d_in[7];
    float* out = (float*)d_out;
    (void)in_sizes; (void)n_in; (void)out_size;

    unsigned short* proj = (unsigned short*)d_ws;
    unsigned short* qT   = proj + (size_t)BN * PROJ_ROWS * NN;
    const size_t baseB = ((size_t)BN * PROJ_ROWS * NN + (size_t)BN * NN * C8) * 2;

    auto needB = [&](int ns) {
        size_t LpB = (size_t)ns * BN * 64 * 64 * 4;
        size_t OpB = (size_t)ns * BN * 64 * CC * 64 * 4;
        return baseB + LpB + OpB;
    };

    proj_kernel<<<256, 256, 0, stream>>>(x, Wq, bq, Wk, bk, Wv, bv, proj, qT);

    if (ws_size >= needB(4)) {
        float* Lpart = (float*)((char*)d_ws + baseB);
        float* Opart = Lpart + (size_t)4 * BN * 64 * 64;
        attn_kernel<4, false><<<1024, 256, 0, stream>>>(proj, qT, x, gamma, out, Opart, Lpart);
        combine_kernel<4><<<1024, 256, 0, stream>>>(Opart, Lpart, x, gamma, out);
    } else if (ws_size >= needB(2)) {
        float* Lpart = (float*)((char*)d_ws + baseB);
        float* Opart = Lpart + (size_t)2 * BN * 64 * 64;
        attn_kernel<2, false><<<512, 256, 0, stream>>>(proj, qT, x, gamma, out, Opart, Lpart);
        combine_kernel<2><<<1024, 256, 0, stream>>>(Opart, Lpart, x, gamma, out);
    } else {
        attn_kernel<1, true><<<256, 256, 0, stream>>>(proj, qT, x, gamma, out, nullptr, nullptr);
    }
}

// Round 4
// 175.868 us; speedup vs baseline: 1.0896x; 1.0896x over previous
//
#include <hip/hip_runtime.h>
#include <hip/hip_bf16.h>

#define BN 4
#define CC 256
#define C8 32
#define NN 4096
#define PROJ_ROWS 320

typedef __attribute__((ext_vector_type(8))) short short8;
typedef __attribute__((ext_vector_type(4))) float f32x4;
typedef __attribute__((ext_vector_type(4))) unsigned short u16x4;

__device__ __forceinline__ unsigned short f2bf(float f) {
    unsigned u = __builtin_bit_cast(unsigned, f);
    unsigned r = (u + 0x7fffu + ((u >> 16) & 1u)) >> 16;
    return (unsigned short)r;
}

__device__ __forceinline__ float bf2f(unsigned short s) {
    return __builtin_bit_cast(float, ((unsigned)s) << 16);
}

// ---------------------------------------------------------------------------
// Projection GEMM, single-barrier version (unchanged from baseline).
// ---------------------------------------------------------------------------
__global__ __launch_bounds__(256) void proj_kernel(
    const float* __restrict__ x,
    const float* __restrict__ Wq, const float* __restrict__ bq,
    const float* __restrict__ Wk, const float* __restrict__ bk,
    const float* __restrict__ Wv, const float* __restrict__ bv,
    unsigned short* __restrict__ proj, unsigned short* __restrict__ qT)
{
    int bid = blockIdx.x;
    int b = bid >> 6, nt = bid & 63;
    int n0 = nt * 64;
    int tid = threadIdx.x;
    int w = tid >> 6, l = tid & 63, l15 = l & 15, lq = l >> 4;

    // Xt[n 64][c 256], stride 264 shorts = 528 B (16B-aligned rows)
    __shared__ alignas(16) unsigned short Xt[64][264];

    int c_l = tid >> 3;          // 0..31
    int nb  = (tid & 7) * 8;     // 0..56

    // stage all 8 c-chunks, then ONE barrier
#pragma unroll
    for (int kc = 0; kc < 8; kc++) {
        const float* xp = x + ((size_t)(b * CC + kc * 32 + c_l)) * NN + n0 + nb;
        float4 x0 = *(const float4*)xp;
        float4 x1 = *(const float4*)(xp + 4);
        float t[8] = {x0.x, x0.y, x0.z, x0.w, x1.x, x1.y, x1.z, x1.w};
#pragma unroll
        for (int e = 0; e < 8; e++) Xt[nb + e][kc * 32 + c_l] = f2bf(t[e]);
    }
    __syncthreads();

    f32x4 acc[5][4];   // wave owns o-groups g = 5w..5w+4 (16 rows each)
#pragma unroll
    for (int gi = 0; gi < 5; gi++)
#pragma unroll
        for (int mi = 0; mi < 4; mi++) acc[gi][mi] = (f32x4){0.f, 0.f, 0.f, 0.f};

    for (int kc = 0; kc < 8; kc++) {
        float4 wf[5][2];
#pragma unroll
        for (int gi = 0; gi < 5; gi++) {
            int og = (w * 5 + gi) * 16 + l15;
            const float* wrow = (og < 32) ? (Wq + (size_t)og * CC)
                              : (og < 64) ? (Wk + (size_t)(og - 32) * CC)
                                          : (Wv + (size_t)(og - 64) * CC);
            const float* wp = wrow + kc * 32 + lq * 8;
            wf[gi][0] = *(const float4*)wp;
            wf[gi][1] = *(const float4*)(wp + 4);
        }
#pragma unroll
        for (int gi = 0; gi < 5; gi++) {
            unsigned short a8[8] __attribute__((aligned(16)));
            float tw[8] = {wf[gi][0].x, wf[gi][0].y, wf[gi][0].z, wf[gi][0].w,
                           wf[gi][1].x, wf[gi][1].y, wf[gi][1].z, wf[gi][1].w};
#pragma unroll
            for (int e = 0; e < 8; e++) a8[e] = f2bf(tw[e]);
            short8 af = *(const short8*)a8;
#pragma unroll
            for (int mi = 0; mi < 4; mi++) {
                short8 bf = *(const short8*)&Xt[mi * 16 + l15][kc * 32 + lq * 8];
                acc[gi][mi] = __builtin_amdgcn_mfma_f32_16x16x32_bf16(af, bf, acc[gi][mi], 0, 0, 0);
            }
        }
    }

    // epilogue: bias + bf16 store. C/D: row = lq*4+r (within group), col = l15.
#pragma unroll
    for (int gi = 0; gi < 5; gi++) {
#pragma unroll
        for (int r = 0; r < 4; r++) {
            int og = (w * 5 + gi) * 16 + lq * 4 + r;
            float bias = (og < 32) ? bq[og] : (og < 64) ? bk[og - 32] : bv[og - 64];
#pragma unroll
            for (int mi = 0; mi < 4; mi++) {
                int n = n0 + mi * 16 + l15;
                unsigned short v16 = f2bf(acc[gi][mi][r] + bias);
                if (og < 32) {
                    qT[((size_t)b * NN + n) * C8 + og] = v16;
                } else {
                    proj[((size_t)b * PROJ_ROWS + og) * NN + n] = v16;
                }
            }
        }
    }
}

// ---------------------------------------------------------------------------
// Flash attention over the query axis (softmax over n), no max subtraction.
// v4 = v1 loop byte-for-byte (64-n per barrier, no stagger, no setprio)
// + SINGLE CHANGE: Opart stored as bf16 (halves split-K intermediate traffic;
// O partials are positive ~1000-term sums later normalized by L, so bf16's
// ~0.2% relative error stays ~0.2% after the divide).
// ---------------------------------------------------------------------------
template<int NSPLIT, bool FINAL>
__global__ __launch_bounds__(256, 4) void attn_kernel(
    const unsigned short* __restrict__ proj,
    const unsigned short* __restrict__ qT,
    const float* __restrict__ x,
    const float* __restrict__ gamma_p,
    float* __restrict__ out,
    unsigned short* __restrict__ Opart,
    float* __restrict__ Lpart)
{
    constexpr int ITERS = 64 / NSPLIT;
    int bid = blockIdx.x;
    int h   = bid >> 8;
    int low = bid & 255;
    int xcd = low & 7;
    int b = xcd >> 1;
    int mtile = ((low >> 3) << 1) | (xcd & 1);
    int m0 = mtile * 64;
    int nbase = h * (ITERS * 64);

    int tid = threadIdx.x;
    int w = tid >> 6, l = tid & 63, l15 = l & 15, lq = l >> 4;

    __shared__ alignas(16) unsigned short ps[2][64][72];  // [buf][m][n]
    __shared__ float red[4][64];
    __shared__ float Ltot[64];

    const unsigned short* kbase = proj + ((size_t)b * PROJ_ROWS + C8) * NN;
    const unsigned short* vbase = proj + ((size_t)b * PROJ_ROWS + 64) * NN;
    const unsigned short* qbase = qT + (size_t)b * NN * C8;

    // k B-operand fragments (held all kernel): lane = k[c8=lq*8+j][m]
    short8 kfrag[4];
#pragma unroll
    for (int mi = 0; mi < 4; mi++) {
        int col = m0 + mi * 16 + l15;
        unsigned short t8[8] __attribute__((aligned(16)));
#pragma unroll
        for (int j = 0; j < 8; j++)
            t8[j] = kbase[(size_t)(lq * 8 + j) * NN + col];
        kfrag[mi] = *(const short8*)t8;
    }

    f32x4 O[4][4];
#pragma unroll
    for (int ci = 0; ci < 4; ci++)
#pragma unroll
        for (int mi = 0; mi < 4; mi++) O[ci][mi] = (f32x4){0.f, 0.f, 0.f, 0.f};
    float runS[4] = {0.f, 0.f, 0.f, 0.f};

    // prologue: S_0, exp, write ps[0]
    {
        short8 qfrag = *(const short8*)(qbase + (size_t)(nbase + 16 * w + l15) * C8 + lq * 8);
#pragma unroll
        for (int mi = 0; mi < 4; mi++) {
            f32x4 S = __builtin_amdgcn_mfma_f32_16x16x32_bf16(
                qfrag, kfrag[mi], (f32x4){0.f, 0.f, 0.f, 0.f}, 0, 0, 0);
            float p0 = __expf(S[0]);
            float p1 = __expf(S[1]);
            float p2 = __expf(S[2]);
            float p3 = __expf(S[3]);
            runS[mi] += (p0 + p1) + (p2 + p3);
            unsigned pk0 = (unsigned)f2bf(p0) | ((unsigned)f2bf(p1) << 16);
            unsigned pk1 = (unsigned)f2bf(p2) | ((unsigned)f2bf(p3) << 16);
            *(uint2*)&ps[0][mi * 16 + l15][16 * w + lq * 4] = make_uint2(pk0, pk1);
        }
    }

    for (int it = 0; it < ITERS; it++) {
        int n0c = nbase + it * 64;
        __syncthreads();  // ps[it&1] visible; WAR on ps[(it+1)&1] cleared

        // PV: O[c,m] += V[c,n] . P[n,m]; wave w owns c in [64w,64w+64).
        const unsigned short* psrc = &ps[it & 1][0][0];
#pragma unroll
        for (int kh = 0; kh < 2; kh++) {
            short8 av[4];
#pragma unroll
            for (int ci = 0; ci < 4; ci++)
                av[ci] = *(const short8*)(vbase
                         + (size_t)(64 * w + ci * 16 + l15) * NN + n0c + kh * 32 + lq * 8);
            short8 bfr[4];
#pragma unroll
            for (int mi = 0; mi < 4; mi++)
                bfr[mi] = *(const short8*)(psrc + (mi * 16 + l15) * 72 + kh * 32 + lq * 8);
#pragma unroll
            for (int ci = 0; ci < 4; ci++)
#pragma unroll
                for (int mi = 0; mi < 4; mi++)
                    O[ci][mi] = __builtin_amdgcn_mfma_f32_16x16x32_bf16(
                        av[ci], bfr[mi], O[ci][mi], 0, 0, 0);
        }

        // S_{it+1}, exp, write ps[(it+1)&1] — hidden until next barrier
        if (it + 1 < ITERS) {
            short8 qfrag = *(const short8*)(qbase
                           + (size_t)(n0c + 64 + 16 * w + l15) * C8 + lq * 8);
            unsigned short* pdst = &ps[(it + 1) & 1][0][0];
#pragma unroll
            for (int mi = 0; mi < 4; mi++) {
                f32x4 S = __builtin_amdgcn_mfma_f32_16x16x32_bf16(
                    qfrag, kfrag[mi], (f32x4){0.f, 0.f, 0.f, 0.f}, 0, 0, 0);
                float p0 = __expf(S[0]);
                float p1 = __expf(S[1]);
                float p2 = __expf(S[2]);
                float p3 = __expf(S[3]);
                runS[mi] += (p0 + p1) + (p2 + p3);
                unsigned pk0 = (unsigned)f2bf(p0) | ((unsigned)f2bf(p1) << 16);
                unsigned pk1 = (unsigned)f2bf(p2) | ((unsigned)f2bf(p3) << 16);
                *(uint2*)(pdst + (mi * 16 + l15) * 72 + 16 * w + lq * 4) = make_uint2(pk0, pk1);
            }
        }
    }

    // column-sum reduction: cross-lane (n row-groups), then cross-wave
#pragma unroll
    for (int mi = 0; mi < 4; mi++) {
        float s = runS[mi];
        s += __shfl_xor(s, 16);
        s += __shfl_xor(s, 32);
        red[w][mi * 16 + l15] = s;
    }
    __syncthreads();
    if (tid < 64) Ltot[tid] = red[0][tid] + red[1][tid] + red[2][tid] + red[3][tid];
    __syncthreads();

    if constexpr (FINAL) {
        float gamma = gamma_p[0];
        float iv[4];
#pragma unroll
        for (int mi = 0; mi < 4; mi++) iv[mi] = 1.0f / Ltot[mi * 16 + l15];
#pragma unroll
        for (int ci = 0; ci < 4; ci++) {
#pragma unroll
            for (int mi = 0; mi < 4; mi++) {
                int m = m0 + mi * 16 + l15;
#pragma unroll
                for (int r = 0; r < 4; r++) {
                    int c = 64 * w + ci * 16 + lq * 4 + r;
                    size_t idx = ((size_t)b * CC + c) * NN + m;
                    out[idx] = gamma * (O[ci][mi][r] * iv[mi]) + x[idx];
                }
            }
        }
    } else {
        size_t p = ((size_t)h * BN + b) * 64 + mtile;
        if (tid < 64) Lpart[p * 64 + tid] = Ltot[tid];
        unsigned short* Ob = Opart + p * (size_t)(CC * 64);
#pragma unroll
        for (int ci = 0; ci < 4; ci++) {
#pragma unroll
            for (int mi = 0; mi < 4; mi++) {
#pragma unroll
                for (int r = 0; r < 4; r++) {
                    int c = 64 * w + ci * 16 + lq * 4 + r;
                    Ob[c * 64 + mi * 16 + l15] = f2bf(O[ci][mi][r]);
                }
            }
        }
    }
}

// ---------------------------------------------------------------------------
// Combine: out = gamma * (sum_h O_h) / (sum_h L_h) + x.  Opart is bf16.
// Grid 1024: one block per (b, mt, c-quarter) for >1 block/CU.
// ---------------------------------------------------------------------------
template<int NSPLIT>
__global__ __launch_bounds__(256) void combine_kernel(
    const unsigned short* __restrict__ Opart, const float* __restrict__ Lpart,
    const float* __restrict__ x, const float* __restrict__ gamma_p,
    float* __restrict__ out)
{
    int bid = blockIdx.x;
    int cq = bid & 3;
    int mt = (bid >> 2) & 63;
    int b  = bid >> 8;
    int tid = threadIdx.x;
    int m4 = tid & 15, c16 = tid >> 4;
    float gamma = gamma_p[0];

    f32x4 Ls = (f32x4){0.f, 0.f, 0.f, 0.f};
#pragma unroll
    for (int h = 0; h < NSPLIT; h++) {
        size_t p = ((size_t)h * BN + b) * 64 + mt;
        Ls += *(const f32x4*)(Lpart + p * 64 + m4 * 4);
    }
    f32x4 inv;
#pragma unroll
    for (int j = 0; j < 4; j++) inv[j] = 1.0f / Ls[j];

#pragma unroll
    for (int cp = 0; cp < 4; cp++) {
        int c = cq * 64 + cp * 16 + c16;
        f32x4 acc = (f32x4){0.f, 0.f, 0.f, 0.f};
#pragma unroll
        for (int h = 0; h < NSPLIT; h++) {
            size_t p = ((size_t)h * BN + b) * 64 + mt;
            u16x4 o4 = *(const u16x4*)(Opart + p * (size_t)(CC * 64) + c * 64 + m4 * 4);
#pragma unroll
            for (int j = 0; j < 4; j++) acc[j] += bf2f(o4[j]);
        }
        size_t idx = ((size_t)b * CC + c) * NN + mt * 64 + m4 * 4;
        f32x4 xv = *(const f32x4*)(x + idx);
        f32x4 o;
#pragma unroll
        for (int j = 0; j < 4; j++) o[j] = gamma * (acc[j] * inv[j]) + xv[j];
        *(f32x4*)(out + idx) = o;
    }
}

extern "C" void kernel_launch(void* const* d_in, const int* in_sizes, int n_in,
                              void* d_out, int out_size, void* d_ws, size_t ws_size,
                              hipStream_t stream) {
    const float* x     = (const float*)d_in[0];
    const float* Wq    = (const float*)d_in[1];
    const float* bq    = (const float*)d_in[2];
    const float* Wk    = (const float*)d_in[3];
    const float* bk    = (const float*)d_in[4];
    const float* Wv    = (const float*)d_in[5];
    const float* bv    = (const float*)d_in[6];
    const float* gamma = (const float*)d_in[7];
    float* out = (float*)d_out;
    (void)in_sizes; (void)n_in; (void)out_size;

    unsigned short* proj = (unsigned short*)d_ws;
    unsigned short* qT   = proj + (size_t)BN * PROJ_ROWS * NN;
    const size_t baseB = ((size_t)BN * PROJ_ROWS * NN + (size_t)BN * NN * C8) * 2;

    auto needB = [&](int ns) {
        size_t LpB = (size_t)ns * BN * 64 * 64 * 4;
        size_t OpB = (size_t)ns * BN * 64 * CC * 64 * 2;   // bf16 Opart
        return baseB + LpB + OpB;
    };

    proj_kernel<<<256, 256, 0, stream>>>(x, Wq, bq, Wk, bk, Wv, bv, proj, qT);

    if (ws_size >= needB(4)) {
        float* Lpart = (float*)((char*)d_ws + baseB);
        unsigned short* Opart = (unsigned short*)(Lpart + (size_t)4 * BN * 64 * 64);
        attn_kernel<4, false><<<1024, 256, 0, stream>>>(proj, qT, x, gamma, out, Opart, Lpart);
        combine_kernel<4><<<1024, 256, 0, stream>>>(Opart, Lpart, x, gamma, out);
    } else if (ws_size >= needB(2)) {
        float* Lpart = (float*)((char*)d_ws + baseB);
        unsigned short* Opart = (unsigned short*)(Lpart + (size_t)2 * BN * 64 * 64);
        attn_kernel<2, false><<<512, 256, 0, stream>>>(proj, qT, x, gamma, out, Opart, Lpart);
        combine_kernel<2><<<1024, 256, 0, stream>>>(Opart, Lpart, x, gamma, out);
    } else {
        attn_kernel<1, true><<<256, 256, 0, stream>>>(proj, qT, x, gamma, out, nullptr, nullptr);
    }
}